// Round 18
// baseline (87.298 us; speedup 1.0000x reference)
//
#include <hip/hip_runtime.h>

// Problem constants
#define Bn  4
#define Cn  128
#define CQn 64
#define Nn  4096

typedef _Float16 h8_t __attribute__((ext_vector_type(8)));
typedef __fp16   p2_t __attribute__((ext_vector_type(2)));   // cvt_pkrtz result type
typedef float    f32x4 __attribute__((ext_vector_type(4)));
typedef unsigned int u32;

// ws layout (bytes):
//  Qh: [B][N][64]  f16 at 0         (2 MB)   Q pre-scaled by log2(e)
//  Kh: [B][N][64]  f16 at 2 MB      (2 MB)
//  Vg: [B][64 jt][128 c][64 pos] f16 at 4 MB (4 MB)  -- fragment-major V
//  pPart: [B][64 it][S][128 c][64 q] f16 at 8 MB   (S x 4 MB)  NORMALIZED o/l
//  pMl:   [B][64 it][S][64 q][2]    f32 after      (S x 128 KB)

#define QKV_BYTES   8388608ull
#define PART_PER_S  4194304ull
#define ML_PER_S    131072ull
#define LOG2E       1.44269504f

// ---------------------------------------------------------------------------
// Kernel 1: fused QKV projection -- R15's PROVEN fp32 kernel, verbatim,
// with one change: Q outputs scaled by LOG2E (exp2-domain softmax downstream).
// V written FRAGMENT-MAJOR per 64-j tile: j at pos = 32h+8g'+(j&3)+4((j>>4)&1),
// g' = (j>>2)&3 (proven rounds 12-15).
// ---------------------------------------------------------------------------
__global__ __launch_bounds__(256) void qkv_proj(
    const float* __restrict__ x,
    const float* __restrict__ Wq, const float* __restrict__ bq,
    const float* __restrict__ Wk, const float* __restrict__ bk,
    const float* __restrict__ Wv, const float* __restrict__ bv,
    _Float16* __restrict__ Qh, _Float16* __restrict__ Kh, _Float16* __restrict__ Vg)
{
    const int ntile = blockIdx.x;
    const int otile = blockIdx.y;
    const int b     = blockIdx.z;
    const int tid   = threadIdx.x;
    const int nbase = ntile * 64;

    __shared__ float Ws[64][132];
    __shared__ float Xs[128][68];

    const float* Wsrc; const float* bsrc; int obase;
    if (otile == 0)      { Wsrc = Wq;                     bsrc = bq;      obase = 0; }
    else if (otile == 1) { Wsrc = Wk;                     bsrc = bk;      obase = 0; }
    else                 { Wsrc = Wv + (otile - 2) * 64 * Cn;
                           bsrc = bv + (otile - 2) * 64;  obase = (otile - 2) * 64; }

    for (int u = 0; u < 8; ++u) {
        int f = tid + u * 256;
        int row = f >> 5;
        int col = (f & 31) * 4;
        *(float4*)&Ws[row][col] = *(const float4*)&Wsrc[row * Cn + col];
    }
    const float* xb = x + ((size_t)b * Cn) * Nn + nbase;
    for (int u = 0; u < 8; ++u) {
        int f = tid + u * 256;
        int c = f >> 4;
        int n = (f & 15) * 4;
        *(float4*)&Xs[c][n] = *(const float4*)&xb[(size_t)c * Nn + n];
    }
    __syncthreads();

    const int o0 = (tid >> 4) * 4;
    const int n0 = (tid & 15) * 4;
    float acc[4][4] = {};

    for (int c = 0; c < Cn; c += 4) {
        float4 w4[4], x4[4];
        for (int oo = 0; oo < 4; ++oo) w4[oo] = *(const float4*)&Ws[o0 + oo][c];
        for (int cc = 0; cc < 4; ++cc) x4[cc] = *(const float4*)&Xs[c + cc][n0];
        for (int oo = 0; oo < 4; ++oo) {
            const float* wv = (const float*)&w4[oo];
            for (int cc = 0; cc < 4; ++cc) {
                const float wsv = wv[cc];
                const float* xp = (const float*)&x4[cc];
                acc[oo][0] += wsv * xp[0];
                acc[oo][1] += wsv * xp[1];
                acc[oo][2] += wsv * xp[2];
                acc[oo][3] += wsv * xp[3];
            }
        }
    }

    float bias[4];
    for (int oo = 0; oo < 4; ++oo) bias[oo] = bsrc[o0 + oo];

    union H4 { _Float16 e[4]; short4 v; };

    if (otile <= 1) {
        _Float16* dst = (otile == 0 ? Qh : Kh) + ((size_t)b * Nn + nbase) * CQn;
        const float sc = (otile == 0) ? LOG2E : 1.f;
        for (int nn = 0; nn < 4; ++nn) {
            H4 h;
            for (int oo = 0; oo < 4; ++oo)
                h.e[oo] = (_Float16)((acc[oo][nn] + bias[oo]) * sc);
            *(short4*)&dst[(size_t)(n0 + nn) * CQn + o0] = h.v;
        }
    } else {
        // Vg[b][ntile][c][pos]
        _Float16* dst = Vg + (size_t)(b * 64 + ntile) * 128 * 64;
        const int og = obase + o0;
        const int a  = n0 >> 2;
        const int h  = a >> 3, qd = a & 7;
        const int pbase = h * 32 + (qd & 3) * 8 + (qd >> 2) * 4;
        for (int oo = 0; oo < 4; ++oo) {
            H4 hh;
            for (int nn = 0; nn < 4; ++nn) hh.e[nn] = (_Float16)(acc[oo][nn] + bias[oo]);
            *(short4*)&dst[(size_t)(og + oo) * 64 + pbase] = hh.v;
        }
    }
}

// ---------------------------------------------------------------------------
// Kernel 2: MFMA flash attention (R15 structure, proven at 52 us), with:
//  - exp2-domain softmax (Q pre-scaled by LOG2E): exp2f, THR 11.54 log2-units
//  - packed v_cvt_pkrtz P conversion
//  - S>1 epilogue stores NORMALIZED (o/l) f16 partials
// LDS 32 KB: K dbuf 2x8 KB + V single 16 KB. 2 barriers/tile.
// ---------------------------------------------------------------------------
__device__ __forceinline__ void gload16(const void* g, void* l) {
    __builtin_amdgcn_global_load_lds(
        (const __attribute__((address_space(1))) u32*)g,
        (__attribute__((address_space(3))) u32*)l, 16, 0, 0);
}

#define KOFF0 0          // K buffer 0: 8 KB
#define KOFF1 8192       // K buffer 1: 8 KB
#define VOFF  16384      // V buffer: 16 KB (single)

__global__ __launch_bounds__(256) void attn_split(
    const _Float16* __restrict__ Qh, const _Float16* __restrict__ Kh,
    const _Float16* __restrict__ Vg, float* __restrict__ out,
    _Float16* __restrict__ pPart, float* __restrict__ pMl, int S)
{
    __shared__ __align__(16) char smem[32768];

    const int tid  = threadIdx.x;
    const int w    = tid >> 6;
    const int lane = tid & 63;
    const int g    = lane >> 4;
    const int ln   = lane & 15;
    const int it   = blockIdx.x;
    const int b    = blockIdx.y;
    const int s    = blockIdx.z;
    const int wib  = it * 64 + w * 16;
    const int njt  = 64 / S;

    const _Float16* qrow = Qh + ((size_t)(b * Nn + wib + ln)) * CQn + 8 * g;
    const h8_t q0 = *(const h8_t*)(qrow);
    const h8_t q1 = *(const h8_t*)(qrow + 32);

    const _Float16* Kb  = Kh + (size_t)b * Nn * CQn;
    const _Float16* Vgb = Vg + (size_t)b * 64 * 8192;

    int ks[2];
    #pragma unroll
    for (int u = 0; u < 2; ++u) {
        int G   = u * 256 + tid;
        int row = G >> 3;
        ks[u] = row * CQn + (((G & 7) ^ (row & 7)) * 8);
    }
    int vs[4];
    #pragma unroll
    for (int u = 0; u < 4; ++u) {
        int G   = u * 256 + tid;
        int row = G >> 3;
        vs[u] = row * 64 + (((G & 7) ^ (row & 7)) * 8);
    }

    const int r7  = ln & 7;
    const int kb0 = ln * 128 + (((    g) ^ r7) << 4);
    const int kb1 = ln * 128 + (((4 + g) ^ r7) << 4);

    auto stageK = [&](int koff, int jt) {
        const _Float16* src = Kb + (size_t)jt * 64 * CQn;
        #pragma unroll
        for (int u = 0; u < 2; ++u)
            gload16(src + ks[u], smem + koff + u * 4096 + w * 1024);
    };
    auto stageV = [&](int jt) {
        const _Float16* src = Vgb + (size_t)jt * 8192;
        #pragma unroll
        for (int u = 0; u < 4; ++u)
            gload16(src + vs[u], smem + VOFF + u * 4096 + w * 1024);
    };

    f32x4 oacc[8];
    #pragma unroll
    for (int i = 0; i < 8; ++i) oacc[i] = (f32x4){0.f, 0.f, 0.f, 0.f};
    float m_run = -3.0e38f, l_run = 0.f;

    const int jt0 = s * njt;
    stageK(KOFF0, jt0);
    stageV(jt0);
    __syncthreads();

    for (int t = 0; t < njt; ++t) {
        if (t + 1 < njt) stageK((t & 1) ? KOFF0 : KOFF1, jt0 + t + 1);

        const char* KU = smem + ((t & 1) ? KOFF1 : KOFF0);
        f32x4 st[4];
        __builtin_amdgcn_s_setprio(1);
        #pragma unroll
        for (int js = 0; js < 4; ++js) {
            h8_t k0 = *(const h8_t*)(KU + kb0 + js * 2048);
            h8_t k1 = *(const h8_t*)(KU + kb1 + js * 2048);
            st[js] = (f32x4){0.f, 0.f, 0.f, 0.f};
            st[js] = __builtin_amdgcn_mfma_f32_16x16x32_f16(k0, q0, st[js], 0, 0, 0);
            st[js] = __builtin_amdgcn_mfma_f32_16x16x32_f16(k1, q1, st[js], 0, 0, 0);
        }
        __builtin_amdgcn_s_setprio(0);

        // online softmax in exp2 domain, defer-max THR = 8*log2e = 11.54
        float tmax = st[0][0];
        #pragma unroll
        for (int js = 0; js < 4; ++js)
            #pragma unroll
            for (int r = 0; r < 4; ++r) tmax = fmaxf(tmax, st[js][r]);
        tmax = fmaxf(tmax, __shfl_xor(tmax, 16));
        tmax = fmaxf(tmax, __shfl_xor(tmax, 32));
        if (__any(tmax > m_run + 11.54f)) {
            const float mnew  = fmaxf(m_run, tmax);
            const float alpha = exp2f(m_run - mnew);
            const float a0 = __shfl(alpha, 4 * g + 0);
            const float a1 = __shfl(alpha, 4 * g + 1);
            const float a2 = __shfl(alpha, 4 * g + 2);
            const float a3 = __shfl(alpha, 4 * g + 3);
            #pragma unroll
            for (int cs = 0; cs < 8; ++cs) {
                oacc[cs][0] *= a0; oacc[cs][1] *= a1;
                oacc[cs][2] *= a2; oacc[cs][3] *= a3;
            }
            l_run *= alpha;
            m_run = mnew;
        }
        float ts = 0.f;
        #pragma unroll
        for (int js = 0; js < 4; ++js)
            #pragma unroll
            for (int r = 0; r < 4; ++r) {
                float p = exp2f(st[js][r] - m_run);
                st[js][r] = p;
                ts += p;
            }
        ts += __shfl_xor(ts, 16);
        ts += __shfl_xor(ts, 32);
        l_run += ts;

        // P fragments via packed cvt (kappa(e,g) = 4g+(e&3)+16*(e>>2))
        union H8P { h8_t h; p2_t p2[4]; };
        H8P p0u, p1u;
        p0u.p2[0] = __builtin_amdgcn_cvt_pkrtz(st[0][0], st[0][1]);
        p0u.p2[1] = __builtin_amdgcn_cvt_pkrtz(st[0][2], st[0][3]);
        p0u.p2[2] = __builtin_amdgcn_cvt_pkrtz(st[1][0], st[1][1]);
        p0u.p2[3] = __builtin_amdgcn_cvt_pkrtz(st[1][2], st[1][3]);
        p1u.p2[0] = __builtin_amdgcn_cvt_pkrtz(st[2][0], st[2][1]);
        p1u.p2[1] = __builtin_amdgcn_cvt_pkrtz(st[2][2], st[2][3]);
        p1u.p2[2] = __builtin_amdgcn_cvt_pkrtz(st[3][0], st[3][1]);
        p1u.p2[3] = __builtin_amdgcn_cvt_pkrtz(st[3][2], st[3][3]);
        const h8_t pa0 = p0u.h;
        const h8_t pa1 = p1u.h;

        __syncthreads();   // bar#1: drains V(t) stage + K(t+1) stage

        __builtin_amdgcn_s_setprio(1);
        #pragma unroll
        for (int cs = 0; cs < 8; ++cs) {
            h8_t v01 = *(const h8_t*)(smem + VOFF + kb0 + cs * 2048);
            h8_t v23 = *(const h8_t*)(smem + VOFF + kb1 + cs * 2048);
            oacc[cs] = __builtin_amdgcn_mfma_f32_16x16x32_f16(pa0, v01, oacc[cs], 0, 0, 0);
            oacc[cs] = __builtin_amdgcn_mfma_f32_16x16x32_f16(pa1, v23, oacc[cs], 0, 0, 0);
        }
        __builtin_amdgcn_s_setprio(0);

        __syncthreads();   // bar#2: V buffer free

        if (t + 1 < njt) stageV(jt0 + t + 1);
    }

    const float lr = 1.f / l_run;
    const float l0 = __shfl(lr, 4 * g + 0);
    const float l1 = __shfl(lr, 4 * g + 1);
    const float l2 = __shfl(lr, 4 * g + 2);
    const float l3 = __shfl(lr, 4 * g + 3);

    if (S == 1) {
        float* ob = out + (size_t)b * Cn * Nn;
        #pragma unroll
        for (int cs = 0; cs < 8; ++cs) {
            float4 o;
            o.x = oacc[cs][0] * l0;
            o.y = oacc[cs][1] * l1;
            o.z = oacc[cs][2] * l2;
            o.w = oacc[cs][3] * l3;
            *(float4*)&ob[(size_t)(cs * 16 + ln) * Nn + wib + 4 * g] = o;
        }
    } else {
        // normalized f16 partials (o/l); combine weights l_s * 2^(m_s-m)
        union H4 { _Float16 e[4]; short4 sv; };
        _Float16* pp = pPart + (((size_t)b * 64 + it) * S + s) * 8192;
        const int qloc = w * 16 + 4 * g;
        #pragma unroll
        for (int cs = 0; cs < 8; ++cs) {
            H4 h;
            h.e[0] = (_Float16)(oacc[cs][0] * l0);
            h.e[1] = (_Float16)(oacc[cs][1] * l1);
            h.e[2] = (_Float16)(oacc[cs][2] * l2);
            h.e[3] = (_Float16)(oacc[cs][3] * l3);
            *(short4*)&pp[(size_t)(cs * 16 + ln) * 64 + qloc] = h.sv;
        }
        if (g == 0) {
            float* ml = pMl + ((((size_t)b * 64 + it) * S + s) * 64 + w * 16 + ln) * 2;
            ml[0] = m_run;
            ml[1] = l_run;
        }
    }
}

// ---------------------------------------------------------------------------
// Kernel 3: flash-combine across S splits (f16 normalized partials).
// out = sum_s w_s * o_s / sum_s w_s, w_s = l_s * 2^(m_s - m).
// ---------------------------------------------------------------------------
__global__ __launch_bounds__(256) void attn_combine(
    const _Float16* __restrict__ pPart, const float* __restrict__ pMl,
    float* __restrict__ out, int S)
{
    const int it  = blockIdx.x;
    const int b   = blockIdx.y;
    const int tid = threadIdx.x;

    __shared__ float wgt[4][64];
    __shared__ float linv[64];

    if (tid < 64) {
        const float* mlb = pMl + (((size_t)b * 64 + it) * S * 64 + tid) * 2;
        float ms[4], ls[4], m = -3.0e38f;
        for (int s = 0; s < S; ++s) {
            ms[s] = mlb[s * 128 + 0];
            ls[s] = mlb[s * 128 + 1];
            m = fmaxf(m, ms[s]);
        }
        float l = 0.f;
        for (int s = 0; s < S; ++s) {
            float wv = ls[s] * exp2f(ms[s] - m);
            wgt[s][tid] = wv;
            l += wv;
        }
        linv[tid] = 1.f / l;
    }
    __syncthreads();

    const int c  = tid >> 1;
    const int q0 = (tid & 1) * 32;
    const _Float16* base = pPart + ((size_t)b * 64 + it) * S * 8192 + (size_t)c * 64 + q0;

    float acc[32];
    #pragma unroll
    for (int k = 0; k < 32; ++k) acc[k] = 0.f;
    for (int s = 0; s < S; ++s) {
        const _Float16* ps = base + (size_t)s * 8192;
        #pragma unroll
        for (int k = 0; k < 32; k += 8) {
            h8_t v = *(const h8_t*)(ps + k);
            #pragma unroll
            for (int j = 0; j < 8; ++j)
                acc[k + j] += wgt[s][q0 + k + j] * (float)v[j];
        }
    }
    float* ob = out + ((size_t)b * Cn + c) * Nn + it * 64 + q0;
    #pragma unroll
    for (int k = 0; k < 32; k += 4) {
        float4 o;
        o.x = acc[k + 0] * linv[q0 + k + 0];
        o.y = acc[k + 1] * linv[q0 + k + 1];
        o.z = acc[k + 2] * linv[q0 + k + 2];
        o.w = acc[k + 3] * linv[q0 + k + 3];
        *(float4*)&ob[k] = o;
    }
}

extern "C" void kernel_launch(void* const* d_in, const int* in_sizes, int n_in,
                              void* d_out, int out_size, void* d_ws, size_t ws_size,
                              hipStream_t stream) {
    const float* x  = (const float*)d_in[0];
    const float* Wq = (const float*)d_in[1];
    const float* bq = (const float*)d_in[2];
    const float* Wk = (const float*)d_in[3];
    const float* bk = (const float*)d_in[4];
    const float* Wv = (const float*)d_in[5];
    const float* bv = (const float*)d_in[6];
    float* out = (float*)d_out;

    _Float16* ws = (_Float16*)d_ws;
    _Float16* Qh = ws;
    _Float16* Kh = ws + 1048576;
    _Float16* Vg = ws + 2097152;

    int S = 1;
    if (ws_size >= QKV_BYTES + 4 * (PART_PER_S + ML_PER_S)) S = 4;
    else if (ws_size >= QKV_BYTES + 2 * (PART_PER_S + ML_PER_S)) S = 2;

    _Float16* pPart = (_Float16*)((char*)d_ws + QKV_BYTES);
    float*    pMl   = (float*)((char*)d_ws + QKV_BYTES + (size_t)S * PART_PER_S);

    dim3 gproj(Nn / 64, 4, Bn);
    qkv_proj<<<gproj, 256, 0, stream>>>(x, Wq, bq, Wk, bk, Wv, bv, Qh, Kh, Vg);

    dim3 gattn(Nn / 64, Bn, S);
    attn_split<<<gattn, 256, 0, stream>>>(Qh, Kh, Vg, out, pPart, pMl, S);

    if (S > 1) {
        dim3 gcomb(Nn / 64, Bn);
        attn_combine<<<gcomb, 256, 0, stream>>>(pPart, pMl, out, S);
    }
}

// Round 19
// 68.666 us; speedup vs baseline: 1.2713x; 1.2713x over previous
//
#include <hip/hip_runtime.h>

// Problem constants
#define Bn  4
#define Cn  128
#define CQn 64
#define Nn  4096

typedef _Float16 h8_t __attribute__((ext_vector_type(8)));
typedef __fp16   p2_t __attribute__((ext_vector_type(2)));   // cvt_pkrtz result type
typedef float    f32x4 __attribute__((ext_vector_type(4)));
typedef unsigned int u32;

// ws layout (bytes):
//  Qh: [B][N][64]  f16 at 0         (2 MB)   Q pre-scaled by log2(e)
//  Kh: [B][N][64]  f16 at 2 MB      (2 MB)
//  Vg: [B][64 jt][128 c][64 pos] f16 at 4 MB (4 MB)  -- fragment-major V
//  pPart: [B][64 it][S][128 c][64 q] f16 at 8 MB   (S x 4 MB)  NORMALIZED o/l
//  pMl:   [B][64 it][S][64 q][2]    f32 after      (S x 128 KB)

#define QKV_BYTES   8388608ull
#define PART_PER_S  4194304ull
#define ML_PER_S    131072ull
#define LOG2E       1.44269504f

// ---------------------------------------------------------------------------
// Kernel 1: QKV projection via MFMA, SINGLE operand-order path (the exact
// fragment pattern attn has verified for 15 rounds):
//   A = W-fragment: lane(g,ln) slot e = W[o = os*16+ln][ch kc*32+8g+e]
//   B = X-fragment: lane(g,ln) slot e = X[ch kc*32+8g+e][n = ns*16+ln]
//   D[row 4g+r][col ln] = y[o = os*16+4g+r][n = ns*16+ln]   (m89 layout)
// Wave w: 0->Q, 1->K, 2,3->V halves. Only the WRITE differs per wave:
//   Q/K: short4 to [n][64ch] (Q scaled by LOG2E).
//   V:   scalar scatter to Vg[c][pos(j)], pos(j) = 32*(j>>5) + 8*((j>>2)&3)
//        + 4*((j>>4)&1) + (j&3)  (R12-15-verified fragment-major formula).
// X staged as TRANSPOSED f16 XsT[n][ch] -> B-fragment = one b128 read.
// os-serialized loop keeps live regs ~50 (no spill under any cap).
// ---------------------------------------------------------------------------
__global__ __launch_bounds__(256) void qkv_proj(
    const float* __restrict__ x,
    const float* __restrict__ Wq, const float* __restrict__ bq,
    const float* __restrict__ Wk, const float* __restrict__ bk,
    const float* __restrict__ Wv, const float* __restrict__ bv,
    _Float16* __restrict__ Qh, _Float16* __restrict__ Kh, _Float16* __restrict__ Vg)
{
    __shared__ _Float16 XsT[64][136];   // [n][ch], 272B row stride (17 granules)

    const int nt   = blockIdx.x;
    const int b    = blockIdx.y;
    const int tid  = threadIdx.x;
    const int w    = tid >> 6;
    const int lane = tid & 63;
    const int g    = lane >> 4;
    const int ln   = lane & 15;
    const int nbase = nt * 64;

    // stage X tile transposed: global [c][n] f32 -> LDS [n][c] f16
    const float* xb = x + (size_t)b * Cn * Nn + nbase;
    #pragma unroll
    for (int u = 0; u < 8; ++u) {
        int f  = tid + u * 256;          // 2048 float4s
        int c  = f >> 4;                 // 0..127
        int n4 = (f & 15) * 4;           // 0..60
        float4 v = *(const float4*)&xb[(size_t)c * Nn + n4];
        XsT[n4 + 0][c] = (_Float16)v.x;
        XsT[n4 + 1][c] = (_Float16)v.y;
        XsT[n4 + 2][c] = (_Float16)v.z;
        XsT[n4 + 3][c] = (_Float16)v.w;
    }
    __syncthreads();

    const float* Wsrc; const float* bsrc;
    if      (w == 0) { Wsrc = Wq;            bsrc = bq;      }
    else if (w == 1) { Wsrc = Wk;            bsrc = bk;      }
    else if (w == 2) { Wsrc = Wv;            bsrc = bv;      }
    else             { Wsrc = Wv + 64 * Cn;  bsrc = bv + 64; }

    union H8 { h8_t h; _Float16 e[8]; };

    #pragma unroll 1
    for (int os = 0; os < 4; ++os) {
        f32x4 acc[4];
        #pragma unroll
        for (int ns = 0; ns < 4; ++ns) acc[ns] = (f32x4){0.f, 0.f, 0.f, 0.f};

        #pragma unroll
        for (int kc = 0; kc < 4; ++kc) {
            // A = W fragment (global f32 -> f16), row = os*16+ln, ch kc*32+8g+e
            const float* wp = Wsrc + (size_t)(os * 16 + ln) * Cn + kc * 32 + 8 * g;
            float4 wa = *(const float4*)wp;
            float4 wb = *(const float4*)(wp + 4);
            H8 t;
            t.e[0] = (_Float16)wa.x; t.e[1] = (_Float16)wa.y;
            t.e[2] = (_Float16)wa.z; t.e[3] = (_Float16)wa.w;
            t.e[4] = (_Float16)wb.x; t.e[5] = (_Float16)wb.y;
            t.e[6] = (_Float16)wb.z; t.e[7] = (_Float16)wb.w;
            const h8_t wf = t.h;
            #pragma unroll
            for (int ns = 0; ns < 4; ++ns) {
                const h8_t xv = *(const h8_t*)&XsT[ns * 16 + ln][kc * 32 + 8 * g];
                acc[ns] = __builtin_amdgcn_mfma_f32_16x16x32_f16(wf, xv, acc[ns], 0, 0, 0);
            }
        }

        if (w <= 1) {
            // Q/K: y[o = os*16+4g+r][n = ns*16+ln] -> dst[n][o], short4 over r
            union H4 { _Float16 e[4]; short4 s; };
            _Float16* dst = (w == 0 ? Qh : Kh) + ((size_t)b * Nn + nbase) * CQn;
            const float sc = (w == 0) ? LOG2E : 1.f;
            float4 bb = *(const float4*)&bsrc[os * 16 + 4 * g];
            #pragma unroll
            for (int ns = 0; ns < 4; ++ns) {
                H4 h;
                h.e[0] = (_Float16)((acc[ns][0] + bb.x) * sc);
                h.e[1] = (_Float16)((acc[ns][1] + bb.y) * sc);
                h.e[2] = (_Float16)((acc[ns][2] + bb.z) * sc);
                h.e[3] = (_Float16)((acc[ns][3] + bb.w) * sc);
                *(short4*)&dst[(size_t)(ns * 16 + ln) * CQn + os * 16 + 4 * g] = h.s;
            }
        } else {
            // V: scalar scatter. c = (w-2)*64 + os*16+4g+r, j = ns*16+ln,
            // pos(j) = 32*(ns>>1) + 8*((4*ns+(ln>>2))&3) + 4*(ns&1) + (ln&3)
            _Float16* dst = Vg + (size_t)(b * 64 + nt) * 8192;
            const int cbase = (w - 2) * 64 + os * 16 + 4 * g;
            #pragma unroll
            for (int ns = 0; ns < 4; ++ns) {
                const int pos = 32 * (ns >> 1) + 8 * ((4 * ns + (ln >> 2)) & 3)
                              + 4 * (ns & 1) + (ln & 3);
                #pragma unroll
                for (int r = 0; r < 4; ++r) {
                    dst[(size_t)(cbase + r) * 64 + pos] =
                        (_Float16)(acc[ns][r] + bsrc[(w == 2 ? 0 : 64) + 0 + os * 16 + 4 * g + r - (w == 2 ? 0 : 64)]);
                }
            }
        }
    }
}

// ---------------------------------------------------------------------------
// Kernel 2: MFMA flash attention (R15 structure), exp2-domain softmax with
// NATIVE __builtin_amdgcn_exp2f (R18's exp2f lowered to precise OCML code:
// VALUBusy 52.5->58.6%, attn 52->59 us -- this reverts that), packed
// cvt_pkrtz P conversion, f16 normalized partials.
// LDS 32 KB: K dbuf 2x8 KB + V single 16 KB. 2 barriers/tile.
// ---------------------------------------------------------------------------
__device__ __forceinline__ void gload16(const void* g, void* l) {
    __builtin_amdgcn_global_load_lds(
        (const __attribute__((address_space(1))) u32*)g,
        (__attribute__((address_space(3))) u32*)l, 16, 0, 0);
}

#define KOFF0 0          // K buffer 0: 8 KB
#define KOFF1 8192       // K buffer 1: 8 KB
#define VOFF  16384      // V buffer: 16 KB (single)

__global__ __launch_bounds__(256) void attn_split(
    const _Float16* __restrict__ Qh, const _Float16* __restrict__ Kh,
    const _Float16* __restrict__ Vg, float* __restrict__ out,
    _Float16* __restrict__ pPart, float* __restrict__ pMl, int S)
{
    __shared__ __align__(16) char smem[32768];

    const int tid  = threadIdx.x;
    const int w    = tid >> 6;
    const int lane = tid & 63;
    const int g    = lane >> 4;
    const int ln   = lane & 15;
    const int it   = blockIdx.x;
    const int b    = blockIdx.y;
    const int s    = blockIdx.z;
    const int wib  = it * 64 + w * 16;
    const int njt  = 64 / S;

    const _Float16* qrow = Qh + ((size_t)(b * Nn + wib + ln)) * CQn + 8 * g;
    const h8_t q0 = *(const h8_t*)(qrow);
    const h8_t q1 = *(const h8_t*)(qrow + 32);

    const _Float16* Kb  = Kh + (size_t)b * Nn * CQn;
    const _Float16* Vgb = Vg + (size_t)b * 64 * 8192;

    int ks[2];
    #pragma unroll
    for (int u = 0; u < 2; ++u) {
        int G   = u * 256 + tid;
        int row = G >> 3;
        ks[u] = row * CQn + (((G & 7) ^ (row & 7)) * 8);
    }
    int vs[4];
    #pragma unroll
    for (int u = 0; u < 4; ++u) {
        int G   = u * 256 + tid;
        int row = G >> 3;
        vs[u] = row * 64 + (((G & 7) ^ (row & 7)) * 8);
    }

    const int r7  = ln & 7;
    const int kb0 = ln * 128 + (((    g) ^ r7) << 4);
    const int kb1 = ln * 128 + (((4 + g) ^ r7) << 4);

    auto stageK = [&](int koff, int jt) {
        const _Float16* src = Kb + (size_t)jt * 64 * CQn;
        #pragma unroll
        for (int u = 0; u < 2; ++u)
            gload16(src + ks[u], smem + koff + u * 4096 + w * 1024);
    };
    auto stageV = [&](int jt) {
        const _Float16* src = Vgb + (size_t)jt * 8192;
        #pragma unroll
        for (int u = 0; u < 4; ++u)
            gload16(src + vs[u], smem + VOFF + u * 4096 + w * 1024);
    };

    f32x4 oacc[8];
    #pragma unroll
    for (int i = 0; i < 8; ++i) oacc[i] = (f32x4){0.f, 0.f, 0.f, 0.f};
    float m_run = -3.0e38f, l_run = 0.f;

    const int jt0 = s * njt;
    stageK(KOFF0, jt0);
    stageV(jt0);
    __syncthreads();

    for (int t = 0; t < njt; ++t) {
        if (t + 1 < njt) stageK((t & 1) ? KOFF0 : KOFF1, jt0 + t + 1);

        const char* KU = smem + ((t & 1) ? KOFF1 : KOFF0);
        f32x4 st[4];
        __builtin_amdgcn_s_setprio(1);
        #pragma unroll
        for (int js = 0; js < 4; ++js) {
            h8_t k0 = *(const h8_t*)(KU + kb0 + js * 2048);
            h8_t k1 = *(const h8_t*)(KU + kb1 + js * 2048);
            st[js] = (f32x4){0.f, 0.f, 0.f, 0.f};
            st[js] = __builtin_amdgcn_mfma_f32_16x16x32_f16(k0, q0, st[js], 0, 0, 0);
            st[js] = __builtin_amdgcn_mfma_f32_16x16x32_f16(k1, q1, st[js], 0, 0, 0);
        }
        __builtin_amdgcn_s_setprio(0);

        // online softmax in exp2 domain, defer-max THR = 8*log2e = 11.54
        float tmax = st[0][0];
        #pragma unroll
        for (int js = 0; js < 4; ++js)
            #pragma unroll
            for (int r = 0; r < 4; ++r) tmax = fmaxf(tmax, st[js][r]);
        tmax = fmaxf(tmax, __shfl_xor(tmax, 16));
        tmax = fmaxf(tmax, __shfl_xor(tmax, 32));
        if (__any(tmax > m_run + 11.54f)) {
            const float mnew  = fmaxf(m_run, tmax);
            const float alpha = __builtin_amdgcn_exp2f(m_run - mnew);
            const float a0 = __shfl(alpha, 4 * g + 0);
            const float a1 = __shfl(alpha, 4 * g + 1);
            const float a2 = __shfl(alpha, 4 * g + 2);
            const float a3 = __shfl(alpha, 4 * g + 3);
            #pragma unroll
            for (int cs = 0; cs < 8; ++cs) {
                oacc[cs][0] *= a0; oacc[cs][1] *= a1;
                oacc[cs][2] *= a2; oacc[cs][3] *= a3;
            }
            l_run *= alpha;
            m_run = mnew;
        }
        float ts = 0.f;
        #pragma unroll
        for (int js = 0; js < 4; ++js)
            #pragma unroll
            for (int r = 0; r < 4; ++r) {
                float p = __builtin_amdgcn_exp2f(st[js][r] - m_run);
                st[js][r] = p;
                ts += p;
            }
        ts += __shfl_xor(ts, 16);
        ts += __shfl_xor(ts, 32);
        l_run += ts;

        // P fragments via packed cvt (kappa(e,g) = 4g+(e&3)+16*(e>>2))
        union H8P { h8_t h; p2_t p2[4]; };
        H8P p0u, p1u;
        p0u.p2[0] = __builtin_amdgcn_cvt_pkrtz(st[0][0], st[0][1]);
        p0u.p2[1] = __builtin_amdgcn_cvt_pkrtz(st[0][2], st[0][3]);
        p0u.p2[2] = __builtin_amdgcn_cvt_pkrtz(st[1][0], st[1][1]);
        p0u.p2[3] = __builtin_amdgcn_cvt_pkrtz(st[1][2], st[1][3]);
        p1u.p2[0] = __builtin_amdgcn_cvt_pkrtz(st[2][0], st[2][1]);
        p1u.p2[1] = __builtin_amdgcn_cvt_pkrtz(st[2][2], st[2][3]);
        p1u.p2[2] = __builtin_amdgcn_cvt_pkrtz(st[3][0], st[3][1]);
        p1u.p2[3] = __builtin_amdgcn_cvt_pkrtz(st[3][2], st[3][3]);
        const h8_t pa0 = p0u.h;
        const h8_t pa1 = p1u.h;

        __syncthreads();   // bar#1: drains V(t) stage + K(t+1) stage

        __builtin_amdgcn_s_setprio(1);
        #pragma unroll
        for (int cs = 0; cs < 8; ++cs) {
            h8_t v01 = *(const h8_t*)(smem + VOFF + kb0 + cs * 2048);
            h8_t v23 = *(const h8_t*)(smem + VOFF + kb1 + cs * 2048);
            oacc[cs] = __builtin_amdgcn_mfma_f32_16x16x32_f16(pa0, v01, oacc[cs], 0, 0, 0);
            oacc[cs] = __builtin_amdgcn_mfma_f32_16x16x32_f16(pa1, v23, oacc[cs], 0, 0, 0);
        }
        __builtin_amdgcn_s_setprio(0);

        __syncthreads();   // bar#2: V buffer free

        if (t + 1 < njt) stageV(jt0 + t + 1);
    }

    const float lr = 1.f / l_run;
    const float l0 = __shfl(lr, 4 * g + 0);
    const float l1 = __shfl(lr, 4 * g + 1);
    const float l2 = __shfl(lr, 4 * g + 2);
    const float l3 = __shfl(lr, 4 * g + 3);

    if (S == 1) {
        float* ob = out + (size_t)b * Cn * Nn;
        #pragma unroll
        for (int cs = 0; cs < 8; ++cs) {
            float4 o;
            o.x = oacc[cs][0] * l0;
            o.y = oacc[cs][1] * l1;
            o.z = oacc[cs][2] * l2;
            o.w = oacc[cs][3] * l3;
            *(float4*)&ob[(size_t)(cs * 16 + ln) * Nn + wib + 4 * g] = o;
        }
    } else {
        union H4 { _Float16 e[4]; short4 sv; };
        _Float16* pp = pPart + (((size_t)b * 64 + it) * S + s) * 8192;
        const int qloc = w * 16 + 4 * g;
        #pragma unroll
        for (int cs = 0; cs < 8; ++cs) {
            H4 h;
            h.e[0] = (_Float16)(oacc[cs][0] * l0);
            h.e[1] = (_Float16)(oacc[cs][1] * l1);
            h.e[2] = (_Float16)(oacc[cs][2] * l2);
            h.e[3] = (_Float16)(oacc[cs][3] * l3);
            *(short4*)&pp[(size_t)(cs * 16 + ln) * 64 + qloc] = h.sv;
        }
        if (g == 0) {
            float* ml = pMl + ((((size_t)b * 64 + it) * S + s) * 64 + w * 16 + ln) * 2;
            ml[0] = m_run;
            ml[1] = l_run;
        }
    }
}

// ---------------------------------------------------------------------------
// Kernel 3: flash-combine across S splits (f16 normalized partials).
// out = sum_s w_s * o_s / sum_s w_s, w_s = l_s * 2^(m_s - m).
// ---------------------------------------------------------------------------
__global__ __launch_bounds__(256) void attn_combine(
    const _Float16* __restrict__ pPart, const float* __restrict__ pMl,
    float* __restrict__ out, int S)
{
    const int it  = blockIdx.x;
    const int b   = blockIdx.y;
    const int tid = threadIdx.x;

    __shared__ float wgt[4][64];
    __shared__ float linv[64];

    if (tid < 64) {
        const float* mlb = pMl + (((size_t)b * 64 + it) * S * 64 + tid) * 2;
        float ms[4], ls[4], m = -3.0e38f;
        for (int s = 0; s < S; ++s) {
            ms[s] = mlb[s * 128 + 0];
            ls[s] = mlb[s * 128 + 1];
            m = fmaxf(m, ms[s]);
        }
        float l = 0.f;
        for (int s = 0; s < S; ++s) {
            float wv = ls[s] * __builtin_amdgcn_exp2f(ms[s] - m);
            wgt[s][tid] = wv;
            l += wv;
        }
        linv[tid] = 1.f / l;
    }
    __syncthreads();

    const int c  = tid >> 1;
    const int q0 = (tid & 1) * 32;
    const _Float16* base = pPart + ((size_t)b * 64 + it) * S * 8192 + (size_t)c * 64 + q0;

    float acc[32];
    #pragma unroll
    for (int k = 0; k < 32; ++k) acc[k] = 0.f;
    for (int s = 0; s < S; ++s) {
        const _Float16* ps = base + (size_t)s * 8192;
        #pragma unroll
        for (int k = 0; k < 32; k += 8) {
            h8_t v = *(const h8_t*)(ps + k);
            #pragma unroll
            for (int j = 0; j < 8; ++j)
                acc[k + j] += wgt[s][q0 + k + j] * (float)v[j];
        }
    }
    float* ob = out + ((size_t)b * Cn + c) * Nn + it * 64 + q0;
    #pragma unroll
    for (int k = 0; k < 32; k += 4) {
        float4 o;
        o.x = acc[k + 0] * linv[q0 + k + 0];
        o.y = acc[k + 1] * linv[q0 + k + 1];
        o.z = acc[k + 2] * linv[q0 + k + 2];
        o.w = acc[k + 3] * linv[q0 + k + 3];
        *(float4*)&ob[k] = o;
    }
}

extern "C" void kernel_launch(void* const* d_in, const int* in_sizes, int n_in,
                              void* d_out, int out_size, void* d_ws, size_t ws_size,
                              hipStream_t stream) {
    const float* x  = (const float*)d_in[0];
    const float* Wq = (const float*)d_in[1];
    const float* bq = (const float*)d_in[2];
    const float* Wk = (const float*)d_in[3];
    const float* bk = (const float*)d_in[4];
    const float* Wv = (const float*)d_in[5];
    const float* bv = (const float*)d_in[6];
    float* out = (float*)d_out;

    _Float16* ws = (_Float16*)d_ws;
    _Float16* Qh = ws;
    _Float16* Kh = ws + 1048576;
    _Float16* Vg = ws + 2097152;

    int S = 1;
    if (ws_size >= QKV_BYTES + 4 * (PART_PER_S + ML_PER_S)) S = 4;
    else if (ws_size >= QKV_BYTES + 2 * (PART_PER_S + ML_PER_S)) S = 2;

    _Float16* pPart = (_Float16*)((char*)d_ws + QKV_BYTES);
    float*    pMl   = (float*)((char*)d_ws + QKV_BYTES + (size_t)S * PART_PER_S);

    dim3 gproj(Nn / 64, Bn);
    qkv_proj<<<gproj, 256, 0, stream>>>(x, Wq, bq, Wk, bk, Wv, bv, Qh, Kh, Vg);

    dim3 gattn(Nn / 64, Bn, S);
    attn_split<<<gattn, 256, 0, stream>>>(Qh, Kh, Vg, out, pPart, pMl, S);

    if (S > 1) {
        dim3 gcomb(Nn / 64, Bn);
        attn_combine<<<gcomb, 256, 0, stream>>>(pPart, pMl, out, S);
    }
}

// Round 20
// 66.223 us; speedup vs baseline: 1.3182x; 1.0369x over previous
//
#include <hip/hip_runtime.h>

// Problem constants
#define Bn  4
#define Cn  128
#define CQn 64
#define Nn  4096

typedef _Float16 h8_t __attribute__((ext_vector_type(8)));
typedef __fp16   p2_t __attribute__((ext_vector_type(2)));   // cvt_pkrtz result type
typedef float    f32x4 __attribute__((ext_vector_type(4)));
typedef unsigned int u32;

// ws layout (bytes):
//  Qh: [B][N][64]  f16 at 0         (2 MB)   Q pre-scaled by log2(e)
//  Kh: [B][N][64]  f16 at 2 MB      (2 MB)
//  Vg: [B][64 jt][128 c][64 pos] f16 at 4 MB (4 MB)  -- fragment-major V
//  pPart: [B][64 it][S][128 c][64 q] f16 at 8 MB   (S x 4 MB)  NORMALIZED o/l
//  pMl:   [B][64 it][S][64 q][2]    f32 after      (S x 128 KB)

#define QKV_BYTES   8388608ull
#define PART_PER_S  4194304ull
#define ML_PER_S    131072ull
#define LOG2E       1.44269504f

// ---------------------------------------------------------------------------
// Kernel 1: QKV projection via MFMA (R19's verified fragment math, verbatim),
// re-gridded for residency: grid (64 nt, 4 ot, B) = 1024 blocks (4/CU; R19's
// 256 blocks = 1/CU left all latency exposed -> ~12.6 us for ~1 us of MFMA).
// Block = output group ot (0=Q, 1=K, 2/3=V halves) x 64-n tile; wave w
// takes os=w. W/X traffic unchanged (each block reads only its W quarter).
//   A = W-fragment: lane(g,ln) slot e = W[o = os*16+ln][ch kc*32+8g+e]
//   B = X-fragment: lane(g,ln) slot e = X[ch kc*32+8g+e][n = ns*16+ln]
//   D[row 4g+r][col ln] = y[o = os*16+4g+r][n = ns*16+ln]
// V scatter: pos(j) = 32*(j>>5) + 8*((j>>2)&3) + 4*((j>>4)&1) + (j&3),
// j = ns*16+ln (R12-19-verified).
// ---------------------------------------------------------------------------
__global__ __launch_bounds__(256) void qkv_proj(
    const float* __restrict__ x,
    const float* __restrict__ Wq, const float* __restrict__ bq,
    const float* __restrict__ Wk, const float* __restrict__ bk,
    const float* __restrict__ Wv, const float* __restrict__ bv,
    _Float16* __restrict__ Qh, _Float16* __restrict__ Kh, _Float16* __restrict__ Vg)
{
    __shared__ _Float16 XsT[64][136];   // [n][ch], 272B row stride

    const int nt   = blockIdx.x;
    const int ot   = blockIdx.y;
    const int b    = blockIdx.z;
    const int tid  = threadIdx.x;
    const int w    = tid >> 6;
    const int lane = tid & 63;
    const int g    = lane >> 4;
    const int ln   = lane & 15;
    const int nbase = nt * 64;

    // stage X tile transposed: global [c][n] f32 -> LDS [n][c] f16
    const float* xb = x + (size_t)b * Cn * Nn + nbase;
    #pragma unroll
    for (int u = 0; u < 8; ++u) {
        int f  = tid + u * 256;          // 2048 float4s
        int c  = f >> 4;                 // 0..127
        int n4 = (f & 15) * 4;           // 0..60
        float4 v = *(const float4*)&xb[(size_t)c * Nn + n4];
        XsT[n4 + 0][c] = (_Float16)v.x;
        XsT[n4 + 1][c] = (_Float16)v.y;
        XsT[n4 + 2][c] = (_Float16)v.z;
        XsT[n4 + 3][c] = (_Float16)v.w;
    }
    __syncthreads();

    const float* Wsrc; const float* bsrc;
    if      (ot == 0) { Wsrc = Wq;            bsrc = bq;      }
    else if (ot == 1) { Wsrc = Wk;            bsrc = bk;      }
    else if (ot == 2) { Wsrc = Wv;            bsrc = bv;      }
    else              { Wsrc = Wv + 64 * Cn;  bsrc = bv + 64; }

    union H8 { h8_t h; _Float16 e[8]; };

    const int os = w;
    f32x4 acc[4];
    #pragma unroll
    for (int ns = 0; ns < 4; ++ns) acc[ns] = (f32x4){0.f, 0.f, 0.f, 0.f};

    #pragma unroll
    for (int kc = 0; kc < 4; ++kc) {
        const float* wp = Wsrc + (size_t)(os * 16 + ln) * Cn + kc * 32 + 8 * g;
        float4 wa = *(const float4*)wp;
        float4 wb = *(const float4*)(wp + 4);
        H8 t;
        t.e[0] = (_Float16)wa.x; t.e[1] = (_Float16)wa.y;
        t.e[2] = (_Float16)wa.z; t.e[3] = (_Float16)wa.w;
        t.e[4] = (_Float16)wb.x; t.e[5] = (_Float16)wb.y;
        t.e[6] = (_Float16)wb.z; t.e[7] = (_Float16)wb.w;
        const h8_t wf = t.h;
        #pragma unroll
        for (int ns = 0; ns < 4; ++ns) {
            const h8_t xv = *(const h8_t*)&XsT[ns * 16 + ln][kc * 32 + 8 * g];
            acc[ns] = __builtin_amdgcn_mfma_f32_16x16x32_f16(wf, xv, acc[ns], 0, 0, 0);
        }
    }

    if (ot <= 1) {
        // Q/K: y[o = os*16+4g+r][n = ns*16+ln] -> dst[n][o], short4 over r
        union H4 { _Float16 e[4]; short4 s; };
        _Float16* dst = (ot == 0 ? Qh : Kh) + ((size_t)b * Nn + nbase) * CQn;
        const float sc = (ot == 0) ? LOG2E : 1.f;
        float4 bb = *(const float4*)&bsrc[os * 16 + 4 * g];
        #pragma unroll
        for (int ns = 0; ns < 4; ++ns) {
            H4 h;
            h.e[0] = (_Float16)((acc[ns][0] + bb.x) * sc);
            h.e[1] = (_Float16)((acc[ns][1] + bb.y) * sc);
            h.e[2] = (_Float16)((acc[ns][2] + bb.z) * sc);
            h.e[3] = (_Float16)((acc[ns][3] + bb.w) * sc);
            *(short4*)&dst[(size_t)(ns * 16 + ln) * CQn + os * 16 + 4 * g] = h.s;
        }
    } else {
        // V: scalar scatter to fragment-major Vg[c][pos(j)]
        _Float16* dst = Vg + (size_t)(b * 64 + nt) * 8192;
        const int cbase = (ot - 2) * 64 + os * 16 + 4 * g;
        #pragma unroll
        for (int ns = 0; ns < 4; ++ns) {
            const int pos = 32 * (ns >> 1) + 8 * ((4 * ns + (ln >> 2)) & 3)
                          + 4 * (ns & 1) + (ln & 3);
            #pragma unroll
            for (int r = 0; r < 4; ++r) {
                dst[(size_t)(cbase + r) * 64 + pos] =
                    (_Float16)(acc[ns][r] + bsrc[os * 16 + 4 * g + r]);
            }
        }
    }
}

// ---------------------------------------------------------------------------
// Kernel 2: MFMA flash attention -- R19 VERBATIM (proven 50.4-50.8 us,
// absmax 0.0703). exp2-domain softmax with native __builtin_amdgcn_exp2f,
// packed cvt_pkrtz P conversion, f16 normalized partials.
// LDS 32 KB: K dbuf 2x8 KB + V single 16 KB. 2 barriers/tile.
// ---------------------------------------------------------------------------
__device__ __forceinline__ void gload16(const void* g, void* l) {
    __builtin_amdgcn_global_load_lds(
        (const __attribute__((address_space(1))) u32*)g,
        (__attribute__((address_space(3))) u32*)l, 16, 0, 0);
}

#define KOFF0 0          // K buffer 0: 8 KB
#define KOFF1 8192       // K buffer 1: 8 KB
#define VOFF  16384      // V buffer: 16 KB (single)

__global__ __launch_bounds__(256) void attn_split(
    const _Float16* __restrict__ Qh, const _Float16* __restrict__ Kh,
    const _Float16* __restrict__ Vg, float* __restrict__ out,
    _Float16* __restrict__ pPart, float* __restrict__ pMl, int S)
{
    __shared__ __align__(16) char smem[32768];

    const int tid  = threadIdx.x;
    const int w    = tid >> 6;
    const int lane = tid & 63;
    const int g    = lane >> 4;
    const int ln   = lane & 15;
    const int it   = blockIdx.x;
    const int b    = blockIdx.y;
    const int s    = blockIdx.z;
    const int wib  = it * 64 + w * 16;
    const int njt  = 64 / S;

    const _Float16* qrow = Qh + ((size_t)(b * Nn + wib + ln)) * CQn + 8 * g;
    const h8_t q0 = *(const h8_t*)(qrow);
    const h8_t q1 = *(const h8_t*)(qrow + 32);

    const _Float16* Kb  = Kh + (size_t)b * Nn * CQn;
    const _Float16* Vgb = Vg + (size_t)b * 64 * 8192;

    int ks[2];
    #pragma unroll
    for (int u = 0; u < 2; ++u) {
        int G   = u * 256 + tid;
        int row = G >> 3;
        ks[u] = row * CQn + (((G & 7) ^ (row & 7)) * 8);
    }
    int vs[4];
    #pragma unroll
    for (int u = 0; u < 4; ++u) {
        int G   = u * 256 + tid;
        int row = G >> 3;
        vs[u] = row * 64 + (((G & 7) ^ (row & 7)) * 8);
    }

    const int r7  = ln & 7;
    const int kb0 = ln * 128 + (((    g) ^ r7) << 4);
    const int kb1 = ln * 128 + (((4 + g) ^ r7) << 4);

    auto stageK = [&](int koff, int jt) {
        const _Float16* src = Kb + (size_t)jt * 64 * CQn;
        #pragma unroll
        for (int u = 0; u < 2; ++u)
            gload16(src + ks[u], smem + koff + u * 4096 + w * 1024);
    };
    auto stageV = [&](int jt) {
        const _Float16* src = Vgb + (size_t)jt * 8192;
        #pragma unroll
        for (int u = 0; u < 4; ++u)
            gload16(src + vs[u], smem + VOFF + u * 4096 + w * 1024);
    };

    f32x4 oacc[8];
    #pragma unroll
    for (int i = 0; i < 8; ++i) oacc[i] = (f32x4){0.f, 0.f, 0.f, 0.f};
    float m_run = -3.0e38f, l_run = 0.f;

    const int jt0 = s * njt;
    stageK(KOFF0, jt0);
    stageV(jt0);
    __syncthreads();

    for (int t = 0; t < njt; ++t) {
        if (t + 1 < njt) stageK((t & 1) ? KOFF0 : KOFF1, jt0 + t + 1);

        const char* KU = smem + ((t & 1) ? KOFF1 : KOFF0);
        f32x4 st[4];
        __builtin_amdgcn_s_setprio(1);
        #pragma unroll
        for (int js = 0; js < 4; ++js) {
            h8_t k0 = *(const h8_t*)(KU + kb0 + js * 2048);
            h8_t k1 = *(const h8_t*)(KU + kb1 + js * 2048);
            st[js] = (f32x4){0.f, 0.f, 0.f, 0.f};
            st[js] = __builtin_amdgcn_mfma_f32_16x16x32_f16(k0, q0, st[js], 0, 0, 0);
            st[js] = __builtin_amdgcn_mfma_f32_16x16x32_f16(k1, q1, st[js], 0, 0, 0);
        }
        __builtin_amdgcn_s_setprio(0);

        // online softmax in exp2 domain, defer-max THR = 8*log2e = 11.54
        float tmax = st[0][0];
        #pragma unroll
        for (int js = 0; js < 4; ++js)
            #pragma unroll
            for (int r = 0; r < 4; ++r) tmax = fmaxf(tmax, st[js][r]);
        tmax = fmaxf(tmax, __shfl_xor(tmax, 16));
        tmax = fmaxf(tmax, __shfl_xor(tmax, 32));
        if (__any(tmax > m_run + 11.54f)) {
            const float mnew  = fmaxf(m_run, tmax);
            const float alpha = __builtin_amdgcn_exp2f(m_run - mnew);
            const float a0 = __shfl(alpha, 4 * g + 0);
            const float a1 = __shfl(alpha, 4 * g + 1);
            const float a2 = __shfl(alpha, 4 * g + 2);
            const float a3 = __shfl(alpha, 4 * g + 3);
            #pragma unroll
            for (int cs = 0; cs < 8; ++cs) {
                oacc[cs][0] *= a0; oacc[cs][1] *= a1;
                oacc[cs][2] *= a2; oacc[cs][3] *= a3;
            }
            l_run *= alpha;
            m_run = mnew;
        }
        float ts = 0.f;
        #pragma unroll
        for (int js = 0; js < 4; ++js)
            #pragma unroll
            for (int r = 0; r < 4; ++r) {
                float p = __builtin_amdgcn_exp2f(st[js][r] - m_run);
                st[js][r] = p;
                ts += p;
            }
        ts += __shfl_xor(ts, 16);
        ts += __shfl_xor(ts, 32);
        l_run += ts;

        // P fragments via packed cvt (kappa(e,g) = 4g+(e&3)+16*(e>>2))
        union H8P { h8_t h; p2_t p2[4]; };
        H8P p0u, p1u;
        p0u.p2[0] = __builtin_amdgcn_cvt_pkrtz(st[0][0], st[0][1]);
        p0u.p2[1] = __builtin_amdgcn_cvt_pkrtz(st[0][2], st[0][3]);
        p0u.p2[2] = __builtin_amdgcn_cvt_pkrtz(st[1][0], st[1][1]);
        p0u.p2[3] = __builtin_amdgcn_cvt_pkrtz(st[1][2], st[1][3]);
        p1u.p2[0] = __builtin_amdgcn_cvt_pkrtz(st[2][0], st[2][1]);
        p1u.p2[1] = __builtin_amdgcn_cvt_pkrtz(st[2][2], st[2][3]);
        p1u.p2[2] = __builtin_amdgcn_cvt_pkrtz(st[3][0], st[3][1]);
        p1u.p2[3] = __builtin_amdgcn_cvt_pkrtz(st[3][2], st[3][3]);
        const h8_t pa0 = p0u.h;
        const h8_t pa1 = p1u.h;

        __syncthreads();   // bar#1: drains V(t) stage + K(t+1) stage

        __builtin_amdgcn_s_setprio(1);
        #pragma unroll
        for (int cs = 0; cs < 8; ++cs) {
            h8_t v01 = *(const h8_t*)(smem + VOFF + kb0 + cs * 2048);
            h8_t v23 = *(const h8_t*)(smem + VOFF + kb1 + cs * 2048);
            oacc[cs] = __builtin_amdgcn_mfma_f32_16x16x32_f16(pa0, v01, oacc[cs], 0, 0, 0);
            oacc[cs] = __builtin_amdgcn_mfma_f32_16x16x32_f16(pa1, v23, oacc[cs], 0, 0, 0);
        }
        __builtin_amdgcn_s_setprio(0);

        __syncthreads();   // bar#2: V buffer free

        if (t + 1 < njt) stageV(jt0 + t + 1);
    }

    const float lr = 1.f / l_run;
    const float l0 = __shfl(lr, 4 * g + 0);
    const float l1 = __shfl(lr, 4 * g + 1);
    const float l2 = __shfl(lr, 4 * g + 2);
    const float l3 = __shfl(lr, 4 * g + 3);

    if (S == 1) {
        float* ob = out + (size_t)b * Cn * Nn;
        #pragma unroll
        for (int cs = 0; cs < 8; ++cs) {
            float4 o;
            o.x = oacc[cs][0] * l0;
            o.y = oacc[cs][1] * l1;
            o.z = oacc[cs][2] * l2;
            o.w = oacc[cs][3] * l3;
            *(float4*)&ob[(size_t)(cs * 16 + ln) * Nn + wib + 4 * g] = o;
        }
    } else {
        union H4 { _Float16 e[4]; short4 sv; };
        _Float16* pp = pPart + (((size_t)b * 64 + it) * S + s) * 8192;
        const int qloc = w * 16 + 4 * g;
        #pragma unroll
        for (int cs = 0; cs < 8; ++cs) {
            H4 h;
            h.e[0] = (_Float16)(oacc[cs][0] * l0);
            h.e[1] = (_Float16)(oacc[cs][1] * l1);
            h.e[2] = (_Float16)(oacc[cs][2] * l2);
            h.e[3] = (_Float16)(oacc[cs][3] * l3);
            *(short4*)&pp[(size_t)(cs * 16 + ln) * 64 + qloc] = h.sv;
        }
        if (g == 0) {
            float* ml = pMl + ((((size_t)b * 64 + it) * S + s) * 64 + w * 16 + ln) * 2;
            ml[0] = m_run;
            ml[1] = l_run;
        }
    }
}

// ---------------------------------------------------------------------------
// Kernel 3: flash-combine across S splits (f16 normalized partials),
// re-gridded: (64 it, B, 2 c-halves) = 512 blocks (was 256 = 1/CU).
// out = sum_s w_s * o_s / sum_s w_s, w_s = l_s * 2^(m_s - m).
// Thread: c = z*64 + (tid>>2), 16 queries at q0 = (tid&3)*16.
// ---------------------------------------------------------------------------
__global__ __launch_bounds__(256) void attn_combine(
    const _Float16* __restrict__ pPart, const float* __restrict__ pMl,
    float* __restrict__ out, int S)
{
    const int it  = blockIdx.x;
    const int b   = blockIdx.y;
    const int ch  = blockIdx.z;      // c half
    const int tid = threadIdx.x;

    __shared__ float wgt[4][64];
    __shared__ float linv[64];

    if (tid < 64) {
        const float* mlb = pMl + (((size_t)b * 64 + it) * S * 64 + tid) * 2;
        float ms[4], ls[4], m = -3.0e38f;
        for (int s = 0; s < S; ++s) {
            ms[s] = mlb[s * 128 + 0];
            ls[s] = mlb[s * 128 + 1];
            m = fmaxf(m, ms[s]);
        }
        float l = 0.f;
        for (int s = 0; s < S; ++s) {
            float wv = ls[s] * __builtin_amdgcn_exp2f(ms[s] - m);
            wgt[s][tid] = wv;
            l += wv;
        }
        linv[tid] = 1.f / l;
    }
    __syncthreads();

    const int c  = ch * 64 + (tid >> 2);
    const int q0 = (tid & 3) * 16;
    const _Float16* base = pPart + ((size_t)b * 64 + it) * S * 8192 + (size_t)c * 64 + q0;

    float acc[16];
    #pragma unroll
    for (int k = 0; k < 16; ++k) acc[k] = 0.f;
    for (int s = 0; s < S; ++s) {
        const _Float16* ps = base + (size_t)s * 8192;
        #pragma unroll
        for (int k = 0; k < 16; k += 8) {
            h8_t v = *(const h8_t*)(ps + k);
            #pragma unroll
            for (int j = 0; j < 8; ++j)
                acc[k + j] += wgt[s][q0 + k + j] * (float)v[j];
        }
    }
    float* ob = out + ((size_t)b * Cn + c) * Nn + it * 64 + q0;
    #pragma unroll
    for (int k = 0; k < 16; k += 4) {
        float4 o;
        o.x = acc[k + 0] * linv[q0 + k + 0];
        o.y = acc[k + 1] * linv[q0 + k + 1];
        o.z = acc[k + 2] * linv[q0 + k + 2];
        o.w = acc[k + 3] * linv[q0 + k + 3];
        *(float4*)&ob[k] = o;
    }
}

extern "C" void kernel_launch(void* const* d_in, const int* in_sizes, int n_in,
                              void* d_out, int out_size, void* d_ws, size_t ws_size,
                              hipStream_t stream) {
    const float* x  = (const float*)d_in[0];
    const float* Wq = (const float*)d_in[1];
    const float* bq = (const float*)d_in[2];
    const float* Wk = (const float*)d_in[3];
    const float* bk = (const float*)d_in[4];
    const float* Wv = (const float*)d_in[5];
    const float* bv = (const float*)d_in[6];
    float* out = (float*)d_out;

    _Float16* ws = (_Float16*)d_ws;
    _Float16* Qh = ws;
    _Float16* Kh = ws + 1048576;
    _Float16* Vg = ws + 2097152;

    int S = 1;
    if (ws_size >= QKV_BYTES + 4 * (PART_PER_S + ML_PER_S)) S = 4;
    else if (ws_size >= QKV_BYTES + 2 * (PART_PER_S + ML_PER_S)) S = 2;

    _Float16* pPart = (_Float16*)((char*)d_ws + QKV_BYTES);
    float*    pMl   = (float*)((char*)d_ws + QKV_BYTES + (size_t)S * PART_PER_S);

    dim3 gproj(Nn / 64, 4, Bn);
    qkv_proj<<<gproj, 256, 0, stream>>>(x, Wq, bq, Wk, bk, Wv, bv, Qh, Kh, Vg);

    dim3 gattn(Nn / 64, Bn, S);
    attn_split<<<gattn, 256, 0, stream>>>(Qh, Kh, Vg, out, pPart, pMl, S);

    if (S > 1) {
        dim3 gcomb(Nn / 64, Bn, 2);
        attn_combine<<<gcomb, 256, 0, stream>>>(pPart, pMl, out, S);
    }
}